// Round 2
// baseline (478.844 us; speedup 1.0000x reference)
//
#include <hip/hip_runtime.h>

#define S_LEN 2048
#define DMODEL 1024
#define NHEADS 8
#define DK 128
#define BATCH 2

typedef _Float16 h16;
typedef __attribute__((ext_vector_type(8))) _Float16 half8v;
typedef __attribute__((ext_vector_type(4))) float float4v;

// async global->LDS, 16B per lane; LDS dest = uniform base + lane*16
#define GLD16(gp, lp)                                                  \
  __builtin_amdgcn_global_load_lds(                                    \
      (const __attribute__((address_space(1))) void*)(gp),             \
      (__attribute__((address_space(3))) void*)(lp), 16, 0, 0)

// Raw barrier + counted waitcnt. sched_barrier(0) guards against hoisting
// (rule #18 defensive). vmcnt(N): allow N youngest vmem ops to stay in flight.
#define BAR_VM0()                                                       \
  do {                                                                  \
    asm volatile("s_waitcnt vmcnt(0) lgkmcnt(0)\ns_barrier" ::: "memory"); \
    __builtin_amdgcn_sched_barrier(0);                                  \
  } while (0)
#define BAR_VM16()                                                      \
  do {                                                                  \
    asm volatile("s_waitcnt vmcnt(16) lgkmcnt(0)\ns_barrier" ::: "memory"); \
    __builtin_amdgcn_sched_barrier(0);                                  \
  } while (0)
#define BAR_LGKM()                                                      \
  do {                                                                  \
    asm volatile("s_waitcnt lgkmcnt(0)\ns_barrier" ::: "memory");       \
    __builtin_amdgcn_sched_barrier(0);                                  \
  } while (0)

// ---------------------------------------------------------------------------
// Fused fp32 -> fp16 pre-conversion for all 7 tensors, one launch.
// ---------------------------------------------------------------------------
__global__ __launch_bounds__(256) void cvt_all(
    const float* __restrict__ q, const float* __restrict__ k, const float* __restrict__ v,
    const float* __restrict__ wq, const float* __restrict__ wk, const float* __restrict__ wv,
    const float* __restrict__ wo,
    h16* __restrict__ dq, h16* __restrict__ dk, h16* __restrict__ dv,
    h16* __restrict__ dwq, h16* __restrict__ dwk, h16* __restrict__ dwv,
    h16* __restrict__ dwo) {
  int i = blockIdx.x * 256 + threadIdx.x;
  const float* src;
  h16* dst;
  int off;
  if (i < 1572864) {
    int seg = i >> 19;
    off = i & 524287;
    src = seg == 0 ? q : (seg == 1 ? k : v);
    dst = seg == 0 ? dq : (seg == 1 ? dk : dv);
  } else {
    int j = i - 1572864;
    int seg = j >> 17;
    off = j & 131071;
    src = seg == 0 ? wq : (seg == 1 ? wk : (seg == 2 ? wv : wo));
    dst = seg == 0 ? dwq : (seg == 1 ? dwk : (seg == 2 ? dwv : dwo));
  }
  const float4* s = (const float4*)src + (size_t)off * 2;
  float4 a = s[0], b = s[1];
  half8v h = {(h16)a.x, (h16)a.y, (h16)a.z, (h16)a.w,
              (h16)b.x, (h16)b.y, (h16)b.z, (h16)b.w};
  *((half8v*)dst + off) = h;
}

// ---------------------------------------------------------------------------
// Fused Q/K/V projection GEMM. Tile 128x128, BK=32, double-buffered LDS,
// single counted barrier per K-step (prefetch overlaps MFMA).
// ---------------------------------------------------------------------------
__global__ __launch_bounds__(256) void qkv_gemm(
    const h16* __restrict__ qf, const h16* __restrict__ kf, const h16* __restrict__ vf,
    const h16* __restrict__ wq, const h16* __restrict__ wk, const h16* __restrict__ wv,
    const float* __restrict__ bq, const float* __restrict__ bk, const float* __restrict__ bv,
    h16* __restrict__ qh, h16* __restrict__ kh, h16* __restrict__ vt) {
  __shared__ h16 As[2][128 * 32];
  __shared__ h16 Bs[2][128 * 32];

  const int z = blockIdx.z;
  const h16* A = z == 0 ? qf : (z == 1 ? kf : vf);
  const h16* Bw = z == 0 ? wq : (z == 1 ? wk : wv);
  const float* bias = z == 0 ? bq : (z == 1 ? bk : bv);
  h16* outp = z == 0 ? qh : (z == 1 ? kh : vt);

  const int t = threadIdx.x, lane = t & 63, w = t >> 6;
  const int m0 = blockIdx.y * 128, n0 = blockIdx.x * 128;
  const int wm = (w >> 1) * 64, wn = (w & 1) * 64;
  const int lcol = lane & 15, lquad = lane >> 4;

  float4v acc[4][4];
  for (int i = 0; i < 4; ++i)
    for (int j = 0; j < 4; ++j) acc[i][j] = {0.f, 0.f, 0.f, 0.f};

#define QKV_STAGE(S, P)                                                    \
  for (int j = 0; j < 2; ++j) {                                            \
    int i = w * 2 + j;                                                     \
    int row = i * 16 + (lane >> 2);                                        \
    int c4 = (lane & 3) ^ ((row >> 1) & 3);                                \
    GLD16(A + (size_t)(m0 + row) * 1024 + (S) * 32 + c4 * 8, As[P] + i * 512); \
    GLD16(Bw + (size_t)(n0 + row) * 1024 + (S) * 32 + c4 * 8, Bs[P] + i * 512); \
  }

  QKV_STAGE(0, 0);
  BAR_VM0();

  for (int s = 0; s < 32; ++s) {
    int sn = s + 1 < 32 ? s + 1 : s;  // clamp: last prefetch lands in dead buf
    QKV_STAGE(sn, (s + 1) & 1);

    const h16* Ar = As[s & 1];
    const h16* Br = Bs[s & 1];
    half8v af[4], bf[4];
    for (int mi = 0; mi < 4; ++mi) {
      int r = wm + mi * 16 + lcol;
      af[mi] = *(const half8v*)(Ar + r * 32 + ((lquad ^ ((r >> 1) & 3)) << 3));
    }
    for (int ni = 0; ni < 4; ++ni) {
      int r = wn + ni * 16 + lcol;
      bf[ni] = *(const half8v*)(Br + r * 32 + ((lquad ^ ((r >> 1) & 3)) << 3));
    }
    for (int mi = 0; mi < 4; ++mi)
      for (int ni = 0; ni < 4; ++ni)
        acc[mi][ni] = __builtin_amdgcn_mfma_f32_16x16x32_f16(af[mi], bf[ni],
                                                             acc[mi][ni], 0, 0, 0);
    BAR_VM0();
  }

  for (int ni = 0; ni < 4; ++ni) {
    int gn = n0 + wn + ni * 16 + lcol;
    float bvv = bias[gn];
    int hh = gn >> 7, dv = gn & 127;
    for (int mi = 0; mi < 4; ++mi) {
      int gmb = m0 + wm + mi * 16 + lquad * 4;
      for (int r = 0; r < 4; ++r) {
        int gm = gmb + r;
        float v = acc[mi][ni][r] + bvv;
        int b = gm >> 11, sdx = gm & 2047;
        if (z < 2)
          outp[((size_t)(b * NHEADS + hh) * S_LEN + sdx) * DK + dv] = (h16)v;
        else
          outp[((size_t)(b * NHEADS + hh) * DK + dv) * S_LEN + sdx] = (h16)v;
      }
    }
  }
}

// ---------------------------------------------------------------------------
// Output projection GEMM: out = ctx @ Wo^T + bo, fp32 out. Same 1-barrier
// double-buffered structure.
// ---------------------------------------------------------------------------
__global__ __launch_bounds__(256) void out_gemm(const h16* __restrict__ A,
                                                const h16* __restrict__ Bw,
                                                const float* __restrict__ bias,
                                                float* __restrict__ C) {
  __shared__ h16 As[2][64 * 32];
  __shared__ h16 Bs[2][128 * 32];

  const int t = threadIdx.x, lane = t & 63, w = t >> 6;
  const int m0 = blockIdx.y * 64, n0 = blockIdx.x * 128;
  const int wm = (w >> 1) * 32, wn = (w & 1) * 64;
  const int lcol = lane & 15, lquad = lane >> 4;

  float4v acc[2][4];
  for (int i = 0; i < 2; ++i)
    for (int j = 0; j < 4; ++j) acc[i][j] = {0.f, 0.f, 0.f, 0.f};

#define OUT_STAGE(S, P)                                                    \
  {                                                                        \
    int row = w * 16 + (lane >> 2);                                        \
    int c4 = (lane & 3) ^ ((row >> 1) & 3);                                \
    GLD16(A + (size_t)(m0 + row) * 1024 + (S) * 32 + c4 * 8, As[P] + w * 512); \
    for (int j = 0; j < 2; ++j) {                                          \
      int i = w * 2 + j;                                                   \
      int row2 = i * 16 + (lane >> 2);                                     \
      int c42 = (lane & 3) ^ ((row2 >> 1) & 3);                            \
      GLD16(Bw + (size_t)(n0 + row2) * 1024 + (S) * 32 + c42 * 8, Bs[P] + i * 512); \
    }                                                                      \
  }

  OUT_STAGE(0, 0);
  BAR_VM0();

  for (int s = 0; s < 32; ++s) {
    int sn = s + 1 < 32 ? s + 1 : s;
    OUT_STAGE(sn, (s + 1) & 1);

    const h16* Ar = As[s & 1];
    const h16* Br = Bs[s & 1];
    half8v af[2], bf[4];
    for (int mi = 0; mi < 2; ++mi) {
      int r = wm + mi * 16 + lcol;
      af[mi] = *(const half8v*)(Ar + r * 32 + ((lquad ^ ((r >> 1) & 3)) << 3));
    }
    for (int ni = 0; ni < 4; ++ni) {
      int r = wn + ni * 16 + lcol;
      bf[ni] = *(const half8v*)(Br + r * 32 + ((lquad ^ ((r >> 1) & 3)) << 3));
    }
    for (int mi = 0; mi < 2; ++mi)
      for (int ni = 0; ni < 4; ++ni)
        acc[mi][ni] = __builtin_amdgcn_mfma_f32_16x16x32_f16(af[mi], bf[ni],
                                                             acc[mi][ni], 0, 0, 0);
    BAR_VM0();
  }

  for (int ni = 0; ni < 4; ++ni) {
    int gn = n0 + wn + ni * 16 + lcol;
    float bvv = bias[gn];
    for (int mi = 0; mi < 2; ++mi) {
      int gmb = m0 + wm + mi * 16 + lquad * 4;
      for (int r = 0; r < 4; ++r)
        C[(size_t)(gmb + r) * 1024 + gn] = acc[mi][ni][r] + bvv;
    }
  }
}

// XCD-aware block swizzle: grid (32,16)=512. xcd = id&7 handles bh in
// {xcd, xcd+8} only -> 2 MB K/V per XCD, L2-resident.
__device__ inline void attn_bid(int& bh, int& q0) {
  int id = blockIdx.y * 32 + blockIdx.x;
  int xcd = id & 7, rank = id >> 3;
  bh = xcd + 8 * (rank >> 5);
  q0 = (rank & 31) * 64;
}

// ---------------------------------------------------------------------------
// Fused attention: one block = (bh, 64 q-rows), 4 waves, Q in registers.
// Phase 1: row sums via col-split QK^T; double-buffered K, 1 barrier/kt.
// Phase 2: per kt: {prefetch K,V -> bufs; QK; P (exp, attn fp32 store, Ps
//   fp16 write); lgkm-barrier; PV; vmcnt(16)-barrier}. The counted vmcnt
//   leaves this kt's 16 attn stores in flight across the barrier -- the
//   268 MB HBM store drains async under the next kt's compute.
// LDS: Ks 2x16K + Vts 2x16K + Ps 9K = 73 KB -> 2 blocks/CU.
// ---------------------------------------------------------------------------
__global__ __launch_bounds__(256, 2) void attn_fused(
    const h16* __restrict__ qh, const h16* __restrict__ kh,
    const h16* __restrict__ vt, float* __restrict__ attn,
    h16* __restrict__ ctxb) {
  __shared__ h16 Ks[2][64 * 128];
  __shared__ h16 Vts[2][128 * 64];
  __shared__ h16 Ps[64 * 72];

  const int t = threadIdx.x, lane = t & 63, w = t >> 6;
  const int lcol = lane & 15, lquad = lane >> 4;
  int bh, q0;
  attn_bid(bh, q0);
  const int b = bh >> 3, h = bh & 7;
  const float scale = 0.08838834764831845f;

#define STAGE_K(KT, BUF)                                                     \
  for (int j = 0; j < 4; ++j) {                                              \
    int i = w * 4 + j;                                                       \
    int row = i * 4 + (lane >> 4);                                           \
    int c4 = (lane & 15) ^ (row & 7);                                        \
    GLD16(kh + ((size_t)bh * S_LEN + (KT) * 64 + row) * DK + c4 * 8,         \
          (BUF) + i * 512);                                                  \
  }
#define STAGE_V(KT, BUF)                                                     \
  for (int j = 0; j < 4; ++j) {                                              \
    int i = w * 4 + j;                                                       \
    int row = i * 8 + (lane >> 3);                                           \
    int c4 = (lane & 7) ^ (row & 7);                                         \
    GLD16(vt + ((size_t)bh * DK + row) * S_LEN + (KT) * 64 + c4 * 8,         \
          (BUF) + i * 512);                                                  \
  }

  // ---- Q preload into registers (staged through Ks[0]) ----
  for (int j = 0; j < 4; ++j) {
    int i = w * 4 + j;
    int row = i * 4 + (lane >> 4);
    int c4 = (lane & 15) ^ (row & 7);
    GLD16(qh + ((size_t)bh * S_LEN + q0 + row) * DK + c4 * 8, Ks[0] + i * 512);
  }
  BAR_VM0();
  // K(0) of phase 1 -> Ks[1], overlapped with aq fragment reads from Ks[0]
  STAGE_K(0, Ks[1]);
  half8v aq[4][4];
  for (int mi = 0; mi < 4; ++mi) {
    int r = mi * 16 + lcol;
    for (int ks = 0; ks < 4; ++ks)
      aq[mi][ks] = *(const half8v*)(Ks[0] + r * 128 + (((ks * 4 + lquad) ^ (r & 7)) << 3));
  }
  BAR_VM0();  // K(0) resident; all waves done reading Q from Ks[0]

  // ---- Phase 1: row sums. K tile s lives in Ks[(s+1)&1]. ----
  float ls[4][4];
  for (int mi = 0; mi < 4; ++mi)
    for (int rr = 0; rr < 4; ++rr) ls[mi][rr] = 0.f;

  for (int s = 0; s < 32; ++s) {
    int sn = s + 1 < 32 ? s + 1 : s;
    STAGE_K(sn, Ks[s & 1]);  // prefetch next into the buffer freed last iter

    const h16* Kr = Ks[(s + 1) & 1];
    float4v sacc[4];
    for (int mi = 0; mi < 4; ++mi) sacc[mi] = {0.f, 0.f, 0.f, 0.f};
    int r = w * 16 + lcol;
    for (int ks = 0; ks < 4; ++ks) {
      half8v bk = *(const half8v*)(Kr + r * 128 + (((ks * 4 + lquad) ^ (r & 7)) << 3));
      for (int mi = 0; mi < 4; ++mi)
        sacc[mi] = __builtin_amdgcn_mfma_f32_16x16x32_f16(aq[mi][ks], bk, sacc[mi], 0, 0, 0);
    }
    for (int mi = 0; mi < 4; ++mi)
      for (int rr = 0; rr < 4; ++rr) ls[mi][rr] += __expf(sacc[mi][rr] * scale);
    BAR_VM0();
  }

  // reduce: over 16 lcol lanes, then cross-wave via LDS (red in Ps)
  float* red = (float*)Ps;  // [4 waves][64 rows]
  for (int mi = 0; mi < 4; ++mi)
    for (int rr = 0; rr < 4; ++rr) {
      float vsum = ls[mi][rr];
      for (int off = 1; off < 16; off <<= 1) vsum += __shfl_xor(vsum, off);
      if (lcol == 0) red[w * 64 + mi * 16 + lquad * 4 + rr] = vsum;
    }
  __syncthreads();
  float il[4][4];
  for (int mi = 0; mi < 4; ++mi)
    for (int rr = 0; rr < 4; ++rr) {
      int row = mi * 16 + lquad * 4 + rr;
      il[mi][rr] = 1.f / (red[row] + red[64 + row] + red[128 + row] + red[192 + row]);
    }

  // ---- Phase 2. K/V tile s lives in Ks[s&1]/Vts[s&1]. ----
  float4v cacc[4][2];
  for (int mi = 0; mi < 4; ++mi)
    for (int nd = 0; nd < 2; ++nd) cacc[mi][nd] = {0.f, 0.f, 0.f, 0.f};

  float* abase = attn + ((size_t)bh * S_LEN + q0 + lquad * 4) * S_LEN + w * 16 + lcol;

  STAGE_K(0, Ks[0]);
  STAGE_V(0, Vts[0]);
  BAR_VM0();

  for (int s = 0; s < 32; ++s) {
    int p = s & 1;
    int sn = s + 1 < 32 ? s + 1 : s;
    // prefetch next K/V (8 GLD16/wave, oldest vmem ops of this iteration)
    STAGE_K(sn, Ks[p ^ 1]);
    STAGE_V(sn, Vts[p ^ 1]);

    // QK for tile s
    const h16* Kr = Ks[p];
    float4v sacc[4];
    for (int mi = 0; mi < 4; ++mi) sacc[mi] = {0.f, 0.f, 0.f, 0.f};
    {
      int r = w * 16 + lcol;
      for (int ks = 0; ks < 4; ++ks) {
        half8v bk = *(const half8v*)(Kr + r * 128 + (((ks * 4 + lquad) ^ (r & 7)) << 3));
        for (int mi = 0; mi < 4; ++mi)
          sacc[mi] = __builtin_amdgcn_mfma_f32_16x16x32_f16(aq[mi][ks], bk, sacc[mi], 0, 0, 0);
      }
    }

    // P-phase: exact fp32 attn stores (left in flight) + fp16 Ps for PV
    h16* Psw = Ps + lquad * 4 * 72 + w * 16 + lcol;
    float* ab = abase + (size_t)s * 64;
    for (int mi = 0; mi < 4; ++mi)
      for (int rr = 0; rr < 4; ++rr) {
        float pv = __expf(sacc[mi][rr] * scale) * il[mi][rr];
        ab[(size_t)(mi * 16 + rr) * S_LEN] = pv;
        Psw[(mi * 16 + rr) * 72] = (h16)pv;
      }

    BAR_LGKM();  // Ps visible to all waves; vmem (prefetch+stores) NOT drained

    // PV for tile s: wave w owns d-cols [32w,32w+32)
    {
      const h16* Vr = Vts[p];
      half8v ap[4][2];
      for (int mi = 0; mi < 4; ++mi)
        for (int k2 = 0; k2 < 2; ++k2)
          ap[mi][k2] = *(const half8v*)(Ps + (mi * 16 + lcol) * 72 + k2 * 32 + lquad * 8);
      for (int nd = 0; nd < 2; ++nd) {
        int r = w * 32 + nd * 16 + lcol;
        for (int k2 = 0; k2 < 2; ++k2) {
          half8v bv = *(const half8v*)(Vr + r * 64 + (((k2 * 4 + lquad) ^ (r & 7)) << 3));
          for (int mi = 0; mi < 4; ++mi)
            cacc[mi][nd] = __builtin_amdgcn_mfma_f32_16x16x32_f16(ap[mi][k2], bv,
                                                                  cacc[mi][nd], 0, 0, 0);
        }
      }
    }

    // vmcnt(16): completes the 8 prefetch GLDs (oldest), leaves this kt's
    // 16 attn stores in flight. lgkm: all waves done reading Ps/Vts[p].
    BAR_VM16();
  }

  h16* cb = ctxb + ((size_t)b * S_LEN + q0 + lquad * 4) * DMODEL + h * DK + w * 32;
  for (int mi = 0; mi < 4; ++mi)
    for (int nd = 0; nd < 2; ++nd)
      for (int rr = 0; rr < 4; ++rr)
        cb[(size_t)(mi * 16 + rr) * DMODEL + nd * 16 + lcol] = (h16)cacc[mi][nd][rr];
}

// ---------------------------------------------------------------------------
extern "C" void kernel_launch(void* const* d_in, const int* in_sizes, int n_in,
                              void* d_out, int out_size, void* d_ws, size_t ws_size,
                              hipStream_t stream) {
  const float* Q  = (const float*)d_in[0];
  const float* K  = (const float*)d_in[1];
  const float* V  = (const float*)d_in[2];
  const float* Wq = (const float*)d_in[3];
  const float* bq = (const float*)d_in[4];
  const float* Wk = (const float*)d_in[5];
  const float* bk = (const float*)d_in[6];
  const float* Wv = (const float*)d_in[7];
  const float* bv = (const float*)d_in[8];
  const float* Wo = (const float*)d_in[9];
  const float* bo = (const float*)d_in[10];

  float* out  = (float*)d_out;
  float* attn = out + (size_t)BATCH * S_LEN * DMODEL;

  const size_t NTOK = (size_t)BATCH * S_LEN * DMODEL;  // 4194304
  const size_t NW = (size_t)DMODEL * DMODEL;           // 1048576
  h16* qf  = (h16*)d_ws;        // later aliased as ctxb
  h16* kf  = qf + NTOK;
  h16* vf  = kf + NTOK;
  h16* wqh = vf + NTOK;
  h16* wkh = wqh + NW;
  h16* wvh = wkh + NW;
  h16* woh = wvh + NW;
  h16* qh  = woh + NW;
  h16* kh  = qh + NTOK;
  h16* vt  = kh + NTOK;
  h16* ctxb = qf;               // safe: qf consumed before attn_fused runs

  dim3 gb(256);
  cvt_all<<<dim3(8192), gb, 0, stream>>>(Q, K, V, Wq, Wk, Wv, Wo,
                                         qf, kf, vf, wqh, wkh, wvh, woh);
  qkv_gemm<<<dim3(8, 32, 3), gb, 0, stream>>>(qf, kf, vf, wqh, wkh, wvh,
                                              bq, bk, bv, qh, kh, vt);
  attn_fused<<<dim3(32, 16), gb, 0, stream>>>(qh, kh, vt, attn, ctxb);
  out_gemm<<<dim3(8, 64), gb, 0, stream>>>(ctxb, woh, bo, out);
}